// Round 9
// baseline (242.106 us; speedup 1.0000x reference)
//
#include <hip/hip_runtime.h>
#include <math.h>

#define BB 2
#define NN 2048
#define MM 4096
#define DD 256
#define HH 8
#define DK 32
#define KNN 16

typedef __attribute__((ext_vector_type(8))) short short8;
typedef __attribute__((ext_vector_type(4))) short short4v;
typedef __attribute__((ext_vector_type(4))) float f32x4;
typedef unsigned long long u64;
typedef unsigned short u16;

static __device__ __forceinline__ u16 f2bf(float f) {
    union { float f; unsigned u; } v; v.f = f;
    unsigned r = v.u + 0x7FFF + ((v.u >> 16) & 1);   // round-to-nearest-even
    return (u16)(r >> 16);
}
static __device__ __forceinline__ float bf2f(u16 u) {
    union { unsigned u; float f; } v; v.u = ((unsigned)u) << 16;
    return v.f;
}

// =================== wtrans: transpose + cvt the five 256x256 weights ===================
__global__ __launch_bounds__(256)
void wtrans(const float* W0, const float* W1, const float* W2, const float* W3, const float* W4,
            u16* O0, u16* O1, u16* O2, u16* O3, u16* O4)
{
    __shared__ float tile[64][65];
    const int bid = blockIdx.x;               // 5 * 16 blocks
    const int m = bid >> 4, tl = bid & 15;
    const int tr = (tl >> 2) * 64, tc = (tl & 3) * 64;
    const float* W = m == 0 ? W0 : m == 1 ? W1 : m == 2 ? W2 : m == 3 ? W3 : W4;
    u16*        O = m == 0 ? O0 : m == 1 ? O1 : m == 2 ? O2 : m == 3 ? O3 : O4;
    const int c = threadIdx.x & 63, r4 = threadIdx.x >> 6;
    #pragma unroll
    for (int i = 0; i < 16; ++i) {
        const int r = (r4 << 4) + i;
        tile[r][c] = W[(size_t)(tr + r) * 256 + tc + c];
    }
    __syncthreads();
    #pragma unroll
    for (int i = 0; i < 16; ++i) {
        const int cc = (r4 << 4) + i;
        O[(size_t)(tc + cc) * 256 + tr + c] = f2bf(tile[c][cc]);
    }
}

// 64x64-tile bf16 MFMA GEMM body; A staged from f32 with inline cvt.
static __device__ __forceinline__ void gemm64_body(
    const float* __restrict__ A, size_t row0, const u16* __restrict__ WT, int col0,
    u16* As, u16* Bs, int t, f32x4 acc[2][2])
{
    const int lane = t & 63, w = t >> 6;
    const int wr = (w >> 1) * 32, wc = (w & 1) * 32;
    for (int k0 = 0; k0 < 256; k0 += 64) {
        #pragma unroll
        for (int e = 0; e < 2; ++e) {
            const int flat = t + (e << 8);
            const int r = flat >> 3, kc = (flat & 7) << 3;
            const int off = ((r << 7) + (kc << 1)) ^ ((r & 7) << 4);
            const float* ap = A + (row0 + r) * 256 + k0 + kc;
            float4 a0 = *(const float4*)ap;
            float4 a1 = *(const float4*)(ap + 4);
            short8 s;
            s[0] = (short)f2bf(a0.x); s[1] = (short)f2bf(a0.y);
            s[2] = (short)f2bf(a0.z); s[3] = (short)f2bf(a0.w);
            s[4] = (short)f2bf(a1.x); s[5] = (short)f2bf(a1.y);
            s[6] = (short)f2bf(a1.z); s[7] = (short)f2bf(a1.w);
            *(short8*)((char*)As + off) = s;
            *(short8*)((char*)Bs + off) = *(const short8*)(WT + (size_t)(col0 + r) * 256 + k0 + kc);
        }
        __syncthreads();
        #pragma unroll
        for (int kk = 0; kk < 64; kk += 32) {
            const int kbo = (kk + ((lane >> 4) << 3)) << 1;
            short8 af[2], bfr[2];
            #pragma unroll
            for (int i = 0; i < 2; ++i) {
                const int ra = wr + (i << 4) + (lane & 15);
                af[i]  = *(const short8*)((const char*)As + (((ra << 7) + kbo) ^ ((ra & 7) << 4)));
                const int rb = wc + (i << 4) + (lane & 15);
                bfr[i] = *(const short8*)((const char*)Bs + (((rb << 7) + kbo) ^ ((rb & 7) << 4)));
            }
            #pragma unroll
            for (int mi = 0; mi < 2; ++mi)
                #pragma unroll
                for (int ni = 0; ni < 2; ++ni)
                    acc[mi][ni] = __builtin_amdgcn_mfma_f32_16x16x32_bf16(af[mi], bfr[ni], acc[mi][ni], 0, 0, 0);
        }
        __syncthreads();
    }
}

// cold path: exhausted lane rescans its 64 candidates for min key strictly > lastPop
static __device__ __forceinline__ unsigned refill_gt(
    const float* __restrict__ tb, int lane, float px, float py, float pz,
    float x2, unsigned lastPop)
{
    unsigned best = 0xFFFFFFFFu;
    #pragma unroll 1
    for (int j = 0; j < 64; ++j) {
        const int m = (j << 6) + lane;
        const float tx = tb[m*3+0], ty = tb[m*3+1], tz = tb[m*3+2];
        const float y2 = tx*tx + ty*ty + tz*tz;
        float d = (x2 + y2) - 2.0f*(px*tx + py*ty + pz*tz);
        d = d > 0.f ? d : 0.f;
        const unsigned k = ((unsigned)fminf(d * 32768.0f, 1048574.0f) << 12) | (unsigned)m;
        if (k > lastPop && k < best) best = k;
    }
    return best;
}

// =================== mega: knn + KV-GEMM + Q-GEMM + zero(avg), role-interleaved ===================
// 2816 blocks = 256 groups x 11 roles: 0-3 knn | 4-7 KV | 8 Q | 9-10 zero
__global__ __launch_bounds__(256, 4)
void mega_kernel(const float* __restrict__ src, const float* __restrict__ tgt,
                 int* __restrict__ knn_idx,
                 const float* __restrict__ tgt_fea, const float* __restrict__ src_fea,
                 const u16* __restrict__ WTq, const u16* __restrict__ WTkv,
                 const float* __restrict__ bq, const float* __restrict__ bk,
                 const float* __restrict__ bv,
                 float* __restrict__ Qb, u16* __restrict__ Kbf, u16* __restrict__ Vbf,
                 float* __restrict__ avg)
{
    __shared__ u16 As[64 * 64];   // 8KB
    __shared__ u16 Bs[64 * 64];   // 8KB
    const int bid = blockIdx.x;
    const int t = threadIdx.x;
    const int lane = t & 63;
    const int lid = bid / 11;
    const int role = bid % 11;

    if (role < 4) {
        // ---- kNN v5: wave-per-query; branchless per-lane sorted cache-2 + 20 pop rounds.
        // Keys unique: (q20<=1048574)<<12 | idx. Pop-by-value; rare masked refill.
        const int kb = lid * 4 + role;                 // 0..1023
        const int bn = (kb << 2) + (t >> 6);           // 0..4095
        const int b = bn >> 11;
        const float* sp = src + (size_t)bn * 3;
        const float px = sp[0], py = sp[1], pz = sp[2];
        const float x2 = px * px + py * py + pz * pz;
        const float* tb = tgt + (size_t)b * MM * 3;
        unsigned s0 = 0xFFFFFFFFu, s1 = 0xFFFFFFFFu;   // sorted: s0 <= s1
        #pragma unroll 8
        for (int j = 0; j < 64; ++j) {
            const int m = (j << 6) + lane;
            const float tx = tb[m * 3 + 0], ty = tb[m * 3 + 1], tz = tb[m * 3 + 2];
            const float y2 = tx * tx + ty * ty + tz * tz;
            float d = (x2 + y2) - 2.0f * (px * tx + py * ty + pz * tz);
            d = d > 0.f ? d : 0.f;
            const unsigned k = ((unsigned)fminf(d * 32768.0f, 1048574.0f) << 12) | (unsigned)m;
            const unsigned hi = k > s0 ? k : s0;       // max(s0,k)
            s0 = k < s0 ? k : s0;                      // min(s0,k)
            s1 = hi < s1 ? hi : s1;                    // min(s1,hi)
        }
        unsigned lastPop = 0;
        unsigned mykey = 0;
        for (int sel = 0; sel < 20; ++sel) {
            if (__any(s0 == 0xFFFFFFFFu)) {            // rare refill of exhausted lanes
                if (s0 == 0xFFFFFFFFu)
                    s0 = refill_gt(tb, lane, px, py, pz, x2, lastPop);
            }
            unsigned best = s0;
            #pragma unroll
            for (int s2 = 32; s2; s2 >>= 1) {
                const unsigned o = __shfl_xor(best, s2, 64);
                best = o < best ? o : best;
            }
            if (lane == sel) mykey = best;
            if (s0 == best) {                          // unique key -> exactly one lane pops
                lastPop = s0;
                s0 = s1;
                s1 = 0xFFFFFFFFu;
            }
        }
        const int midx = (int)(mykey & 0xFFFu);
        u64 ex = ~0ULL;
        if (lane < 20) {                               // exact f64 distance, np-order key
            const float* tp = tb + (size_t)midx * 3;
            const double pxd = px, pyd = py, pzd = pz;
            const double tx = tp[0], ty = tp[1], tz = tp[2];
            const double x2d = pxd * pxd + pyd * pyd + pzd * pzd;
            const double y2d = tx * tx + ty * ty + tz * tz;
            const double dtd = pxd * tx + pyd * ty + pzd * tz;
            double dd = (x2d + y2d) - 2.0 * dtd;
            dd = dd > 0.0 ? dd : 0.0;
            ex = (((u64)__double_as_longlong(dd)) & ~0xFFFULL) | (u64)midx;
        }
        int rank = 0;
        #pragma unroll
        for (int i = 0; i < 20; ++i) {
            const u64 o = __shfl(ex, i, 64);
            rank += (o < ex) ? 1 : 0;
        }
        if (lane < 20 && rank < 16)
            knn_idx[(size_t)bn * KNN + rank] = midx;
        return;
    }

    if (role < 8) {
        // ---- KV GEMM: [8192][512] = tgt_fea @ [WTk|WTv]^T, bf16 out, 64x64 tile
        const int kvb = lid * 4 + (role - 4);          // 0..1023
        const size_t row0 = (size_t)(kvb >> 3) * 64;
        const int col0 = (kvb & 7) * 64;
        f32x4 acc[2][2] = {};
        gemm64_body(tgt_fea, row0, WTkv, col0, As, Bs, t, acc);
        const int w = t >> 6;
        const int wr = (w >> 1) * 32, wc = (w & 1) * 32;
        const bool isv = col0 >= 256;
        u16* ob = isv ? Vbf : Kbf;
        const float* bs = isv ? bv : bk;
        const int cb = (isv ? col0 - 256 : col0) + wc;
        const int cq = lane & 15, rq = (lane >> 4) << 2;
        #pragma unroll
        for (int ni = 0; ni < 2; ++ni) {
            const int c = cb + (ni << 4) + cq;
            const float bval = bs[c];
            #pragma unroll
            for (int mi = 0; mi < 2; ++mi) {
                const size_t r = row0 + wr + (mi << 4) + rq;
                #pragma unroll
                for (int e = 0; e < 4; ++e)
                    ob[(r + e) * 256 + c] = f2bf(acc[mi][ni][e] + bval);
            }
        }
        return;
    }

    if (role == 8) {
        // ---- Q GEMM: [4096][256] f32 = src_fea @ WTq^T, 64x64 tile
        const int qb = lid;                            // 0..255
        const size_t row0 = (size_t)(qb >> 2) * 64;
        const int col0 = (qb & 3) * 64;
        f32x4 acc[2][2] = {};
        gemm64_body(src_fea, row0, WTq, col0, As, Bs, t, acc);
        const int w = t >> 6;
        const int wr = (w >> 1) * 32, wc = (w & 1) * 32;
        const int cq = lane & 15, rq = (lane >> 4) << 2;
        #pragma unroll
        for (int ni = 0; ni < 2; ++ni) {
            const int c = col0 + wc + (ni << 4) + cq;
            const float bval = bq[c];
            #pragma unroll
            for (int mi = 0; mi < 2; ++mi) {
                const size_t rbase = (row0 + wr + (mi << 4) + rq) * 256 + c;
                #pragma unroll
                for (int e = 0; e < 4; ++e)
                    Qb[rbase + (size_t)e * 256] = acc[mi][ni][e] + bval;
            }
        }
        return;
    }

    // ---- zero avg_attn: 16.78M f32 via f32x4
    {
        const int zb = lid * 2 + (role - 9);           // 0..511
        f32x4 z = {0.f, 0.f, 0.f, 0.f};
        f32x4* pz = (f32x4*)avg;
        const int base = zb * 256 + t;
        #pragma unroll
        for (int i = 0; i < 32; ++i)
            pz[base + i * 131072] = z;
    }
}

// =================== tail v2: attn + Wo1+LN+ReLU + Wo2 fused; 1024 blocks x 256 thr ===================
// Block owns 4 rows (4 waves, 1 query/wave). GEMMs: M=16 MFMA with Xs/Hs rows 4-15 zero-padded;
// each wave covers 64 cols = 4 strips of 16.
__global__ __launch_bounds__(256)
void tail_kernel(const float* __restrict__ Q, const u16* __restrict__ Kb,
                 const u16* __restrict__ Vb, const int* __restrict__ knn_idx,
                 const float* __restrict__ src_fea,
                 const u16* __restrict__ WTo1, const float* __restrict__ bo1,
                 const float* __restrict__ lng, const float* __restrict__ lnb,
                 const u16* __restrict__ WTo2, const float* __restrict__ bo2,
                 float* __restrict__ updated, float* __restrict__ avg_attn)
{
    __shared__ float q_sh[4][256];         // 4KB
    __shared__ float pw_sh[4][8][17];      // 2.2KB
    __shared__ int   idx_sh[4][16];        // 256B
    __shared__ u16   Xs[16 * 256];         // 8KB, XOR-swizzled rows; rows 4-15 zero
    __shared__ u16   Hs[16 * 256];         // 8KB, same
    __shared__ float2 red2[4][4];          // [wave][row] partial (s1,s2)
    const int t = threadIdx.x;
    const int w = t >> 6, lane = t & 63;
    const int r0 = blockIdx.x << 2;
    const int bn = r0 + w;
    const int b = bn >> 11;
    const int h = lane >> 3, k2 = lane & 7;

    {   // zero rows 4..15 of Xs and Hs (bytes [2048,8192) = u32 [512,2048))
        unsigned* xz = (unsigned*)Xs;
        unsigned* hz = (unsigned*)Hs;
        #pragma unroll
        for (int i = 0; i < 6; ++i) {
            xz[512 + t + i * 256] = 0u;
            hz[512 + t + i * 256] = 0u;
        }
    }

    // ---- attn: one query per wave (intra-wave LDS only; no barrier needed until Xs) ----
    *(float4*)&q_sh[w][lane << 2] = *(const float4*)(Q + (size_t)bn * 256 + (lane << 2));
    const int ia = knn_idx[(size_t)bn * KNN + k2];
    const int ib = knn_idx[(size_t)bn * KNN + 8 + k2];

    const u16* Ka = Kb + ((size_t)b * MM + ia) * 256 + h * DK;
    const u16* Kc = Kb + ((size_t)b * MM + ib) * 256 + h * DK;
    const float* qh = &q_sh[w][h * DK];
    float s0 = 0.f, s1 = 0.f;
    #pragma unroll
    for (int j = 0; j < DK; j += 8) {
        const short8 ka = *(const short8*)(Ka + j);
        const short8 kc = *(const short8*)(Kc + j);
        #pragma unroll
        for (int e = 0; e < 8; ++e) {
            const float qv = qh[j + e];
            s0 = fmaf(qv, bf2f((u16)ka[e]), s0);
            s1 = fmaf(qv, bf2f((u16)kc[e]), s1);
        }
    }
    s0 *= 0.17677669529663688f;
    s1 *= 0.17677669529663688f;

    float mx = fmaxf(s0, s1);
    mx = fmaxf(mx, __shfl_xor(mx, 1, 64));
    mx = fmaxf(mx, __shfl_xor(mx, 2, 64));
    mx = fmaxf(mx, __shfl_xor(mx, 4, 64));
    const float e0 = expf(s0 - mx), e1 = expf(s1 - mx);
    float sum = e0 + e1;
    sum += __shfl_xor(sum, 1, 64);
    sum += __shfl_xor(sum, 2, 64);
    sum += __shfl_xor(sum, 4, 64);
    const float inv = 1.0f / sum;
    const float p0 = e0 * inv, p1 = e1 * inv;

    float a0 = p0, a1 = p1;
    a0 += __shfl_xor(a0, 8, 64);  a1 += __shfl_xor(a1, 8, 64);
    a0 += __shfl_xor(a0, 16, 64); a1 += __shfl_xor(a1, 16, 64);
    a0 += __shfl_xor(a0, 32, 64); a1 += __shfl_xor(a1, 32, 64);
    if (h == 0) {
        avg_attn[(size_t)bn * MM + ia] = a0 * 0.125f;
        avg_attn[(size_t)bn * MM + ib] = a1 * 0.125f;
        idx_sh[w][k2] = ia;
        idx_sh[w][8 + k2] = ib;
    }
    pw_sh[w][h][k2] = p0;
    pw_sh[w][h][8 + k2] = p1;

    {   // PV + residual -> Xs row w (bf16, swizzled)
        const int d0 = lane << 2;
        const int h2 = lane >> 3;
        float o0 = 0.f, o1 = 0.f, o2 = 0.f, o3 = 0.f;
        #pragma unroll
        for (int k = 0; k < KNN; ++k) {
            const float p = pw_sh[w][h2][k];
            const int ik = idx_sh[w][k];
            const short4v v4 = *(const short4v*)(Vb + ((size_t)b * MM + ik) * 256 + d0);
            o0 = fmaf(p, bf2f((u16)v4[0]), o0);
            o1 = fmaf(p, bf2f((u16)v4[1]), o1);
            o2 = fmaf(p, bf2f((u16)v4[2]), o2);
            o3 = fmaf(p, bf2f((u16)v4[3]), o3);
        }
        const float4 sf = *(const float4*)(src_fea + (size_t)bn * 256 + d0);
        short4v xo;
        xo[0] = (short)f2bf(o0 + sf.x);
        xo[1] = (short)f2bf(o1 + sf.y);
        xo[2] = (short)f2bf(o2 + sf.z);
        xo[3] = (short)f2bf(o3 + sf.w);
        const int off = ((w << 9) + (d0 << 1)) ^ ((w & 7) << 4);
        *(short4v*)((char*)Xs + off) = xo;
    }
    __syncthreads();

    // ---- Wo1 (M=16, rows 4-15 zero) + bias; wave covers 64 cols = 4 strips ----
    const int cq = lane & 15, ks = lane >> 4;
    f32x4 acc1[4] = {};
    #pragma unroll
    for (int s = 0; s < 4; ++s) {
        const int colB = (w << 6) + (s << 4) + cq;
        const u16* bp = WTo1 + (size_t)colB * 256;
        #pragma unroll
        for (int kk = 0; kk < 256; kk += 32) {
            const int k8 = kk + (ks << 3);
            const short8 af = *(const short8*)((const char*)Xs + (((cq << 9) + (k8 << 1)) ^ ((cq & 7) << 4)));
            const short8 bfrg = *(const short8*)(bp + k8);
            acc1[s] = __builtin_amdgcn_mfma_f32_16x16x32_bf16(af, bfrg, acc1[s], 0, 0, 0);
        }
        const float bval = bo1[colB];
        #pragma unroll
        for (int e = 0; e < 4; ++e) acc1[s][e] += bval;
    }
    {   // per-row (rows 0-3, ks==0 lanes) partial sums over this wave's 64 cols
        #pragma unroll
        for (int e = 0; e < 4; ++e) {
            float v = acc1[0][e] + acc1[1][e] + acc1[2][e] + acc1[3][e];
            float vv = acc1[0][e]*acc1[0][e] + acc1[1][e]*acc1[1][e]
                     + acc1[2][e]*acc1[2][e] + acc1[3][e]*acc1[3][e];
            v += __shfl_xor(v, 1, 64); vv += __shfl_xor(vv, 1, 64);
            v += __shfl_xor(v, 2, 64); vv += __shfl_xor(vv, 2, 64);
            v += __shfl_xor(v, 4, 64); vv += __shfl_xor(vv, 4, 64);
            v += __shfl_xor(v, 8, 64); vv += __shfl_xor(vv, 8, 64);
            if (ks == 0 && cq == 0) {
                float2 pr; pr.x = v; pr.y = vv;
                red2[w][e] = pr;
            }
        }
    }
    __syncthreads();
    if (ks == 0) {  // LN + ReLU -> Hs rows 0-3
        float g4[4], b4[4];
        #pragma unroll
        for (int s = 0; s < 4; ++s) {
            const int colB = (w << 6) + (s << 4) + cq;
            g4[s] = lng[colB]; b4[s] = lnb[colB];
        }
        #pragma unroll
        for (int e = 0; e < 4; ++e) {
            float S1 = 0.f, S2 = 0.f;
            #pragma unroll
            for (int w2 = 0; w2 < 4; ++w2) {
                const float2 pr = red2[w2][e];
                S1 += pr.x; S2 += pr.y;
            }
            const float mean = S1 * (1.0f / 256.0f);
            const float var = S2 * (1.0f / 256.0f) - mean * mean;
            const float rstd = 1.0f / sqrtf(var + 1e-5f);
            #pragma unroll
            for (int s = 0; s < 4; ++s) {
                const int colB = (w << 6) + (s << 4) + cq;
                const float y = (acc1[s][e] - mean) * rstd * g4[s] + b4[s];
                const int off = ((e << 9) + (colB << 1)) ^ ((e & 7) << 4);
                *(u16*)((char*)Hs + off) = f2bf(fmaxf(y, 0.0f));
            }
        }
    }
    __syncthreads();

    // ---- Wo2 (M=16, rows 4-15 zero) -> updated rows r0..r0+3 ----
    #pragma unroll
    for (int s = 0; s < 4; ++s) {
        const int colB = (w << 6) + (s << 4) + cq;
        const u16* bp = WTo2 + (size_t)colB * 256;
        f32x4 acc2 = {};
        #pragma unroll
        for (int kk = 0; kk < 256; kk += 32) {
            const int k8 = kk + (ks << 3);
            const short8 af = *(const short8*)((const char*)Hs + (((cq << 9) + (k8 << 1)) ^ ((cq & 7) << 4)));
            const short8 bfrg = *(const short8*)(bp + k8);
            acc2 = __builtin_amdgcn_mfma_f32_16x16x32_bf16(af, bfrg, acc2, 0, 0, 0);
        }
        if (ks == 0) {
            const float bval = bo2[colB];
            #pragma unroll
            for (int e = 0; e < 4; ++e)
                updated[(size_t)(r0 + e) * 256 + colB] = acc2[e] + bval;
        }
    }
}

extern "C" void kernel_launch(void* const* d_in, const int* in_sizes, int n_in,
                              void* d_out, int out_size, void* d_ws, size_t ws_size,
                              hipStream_t stream) {
    const float* src     = (const float*)d_in[0];
    const float* tgt     = (const float*)d_in[1];
    const float* src_fea = (const float*)d_in[2];
    const float* tgt_fea = (const float*)d_in[3];
    const float* Wq  = (const float*)d_in[4];   const float* bq  = (const float*)d_in[5];
    const float* Wk  = (const float*)d_in[6];   const float* bk  = (const float*)d_in[7];
    const float* Wv  = (const float*)d_in[8];   const float* bv  = (const float*)d_in[9];
    const float* Wo1 = (const float*)d_in[10];  const float* bo1 = (const float*)d_in[11];
    const float* lng = (const float*)d_in[12];  const float* lnb = (const float*)d_in[13];
    const float* Wo2 = (const float*)d_in[14];  const float* bo2 = (const float*)d_in[15];
    (void)in_sizes; (void)n_in; (void)out_size; (void)ws_size;

    float* out     = (float*)d_out;
    float* updated = out;                                   // [B,N,D] f32
    float* avg     = out + (size_t)BB * NN * DD;            // [B,N,M] f32

    char* p = (char*)d_ws;
    u16* WTq  = (u16*)p;   p += 256 * 256 * 2;
    u16* WTk  = (u16*)p;   p += 256 * 256 * 2;              // WTk|WTv contiguous = WTkv
    u16* WTv  = (u16*)p;   p += 256 * 256 * 2;
    u16* WTo1 = (u16*)p;   p += 256 * 256 * 2;
    u16* WTo2 = (u16*)p;   p += 256 * 256 * 2;
    float* Qb = (float*)p; p += (size_t)BB * NN * DD * 4;   // 4MB
    u16* Kbf  = (u16*)p;   p += (size_t)BB * MM * DD * 2;   // 4MB
    u16* Vbf  = (u16*)p;   p += (size_t)BB * MM * DD * 2;   // 4MB
    int* knn  = (int*)p;   p += (size_t)BB * NN * KNN * 4;  // 256KB

    dim3 blk(256);
    wtrans<<<80, blk, 0, stream>>>(Wq, Wk, Wv, Wo1, Wo2, WTq, WTk, WTv, WTo1, WTo2);
    mega_kernel<<<2816, blk, 0, stream>>>(src, tgt, knn, tgt_fea, src_fea, WTq, WTk,
                                          bq, bk, bv, Qb, Kbf, Vbf, avg);
    tail_kernel<<<1024, blk, 0, stream>>>(Qb, Kbf, Vbf, knn, src_fea,
                                          WTo1, bo1, lng, lnb, WTo2, bo2,
                                          updated, avg);
}

// Round 10
// 184.432 us; speedup vs baseline: 1.3127x; 1.3127x over previous
//
#include <hip/hip_runtime.h>
#include <math.h>

#define BB 2
#define NN 2048
#define MM 4096
#define DD 256
#define HH 8
#define DK 32
#define KNN 16

typedef __attribute__((ext_vector_type(8))) short short8;
typedef __attribute__((ext_vector_type(4))) short short4v;
typedef __attribute__((ext_vector_type(4))) float f32x4;
typedef unsigned long long u64;
typedef unsigned short u16;

static __device__ __forceinline__ u16 f2bf(float f) {
    union { float f; unsigned u; } v; v.f = f;
    unsigned r = v.u + 0x7FFF + ((v.u >> 16) & 1);   // round-to-nearest-even
    return (u16)(r >> 16);
}
static __device__ __forceinline__ float bf2f(u16 u) {
    union { unsigned u; float f; } v; v.u = ((unsigned)u) << 16;
    return v.f;
}

// =================== prep: weight transpose+cvt (blocks 0-79) + tgt4 pack (blocks 80-111) ===================
__global__ __launch_bounds__(256)
void prep(const float* W0, const float* W1, const float* W2, const float* W3, const float* W4,
          u16* O0, u16* O1, u16* O2, u16* O3, u16* O4,
          const float* __restrict__ tgt, float4* __restrict__ tgt4)
{
    __shared__ float tile[64][65];
    const int bid = blockIdx.x;
    const int t = threadIdx.x;
    if (bid >= 80) {                         // pack tgt -> (x,y,z,|y|^2)
        const int i = (bid - 80) * 256 + t;  // 0..8191
        const float x = tgt[i * 3 + 0], y = tgt[i * 3 + 1], z = tgt[i * 3 + 2];
        float4 o; o.x = x; o.y = y; o.z = z; o.w = x * x + y * y + z * z;
        tgt4[i] = o;
        return;
    }
    const int m = bid >> 4, tl = bid & 15;
    const int tr = (tl >> 2) * 64, tc = (tl & 3) * 64;
    const float* W = m == 0 ? W0 : m == 1 ? W1 : m == 2 ? W2 : m == 3 ? W3 : W4;
    u16*        O = m == 0 ? O0 : m == 1 ? O1 : m == 2 ? O2 : m == 3 ? O3 : O4;
    const int c = t & 63, r4 = t >> 6;
    #pragma unroll
    for (int i = 0; i < 16; ++i) {
        const int r = (r4 << 4) + i;
        tile[r][c] = W[(size_t)(tr + r) * 256 + tc + c];
    }
    __syncthreads();
    #pragma unroll
    for (int i = 0; i < 16; ++i) {
        const int cc = (r4 << 4) + i;
        O[(size_t)(tc + cc) * 256 + tr + c] = f2bf(tile[c][cc]);
    }
}

// 64x64-tile bf16 MFMA GEMM body; A staged from f32 with inline cvt.
static __device__ __forceinline__ void gemm64_body(
    const float* __restrict__ A, size_t row0, const u16* __restrict__ WT, int col0,
    u16* As, u16* Bs, int t, f32x4 acc[2][2])
{
    const int lane = t & 63, w = t >> 6;
    const int wr = (w >> 1) * 32, wc = (w & 1) * 32;
    for (int k0 = 0; k0 < 256; k0 += 64) {
        #pragma unroll
        for (int e = 0; e < 2; ++e) {
            const int flat = t + (e << 8);
            const int r = flat >> 3, kc = (flat & 7) << 3;
            const int off = ((r << 7) + (kc << 1)) ^ ((r & 7) << 4);
            const float* ap = A + (row0 + r) * 256 + k0 + kc;
            float4 a0 = *(const float4*)ap;
            float4 a1 = *(const float4*)(ap + 4);
            short8 s;
            s[0] = (short)f2bf(a0.x); s[1] = (short)f2bf(a0.y);
            s[2] = (short)f2bf(a0.z); s[3] = (short)f2bf(a0.w);
            s[4] = (short)f2bf(a1.x); s[5] = (short)f2bf(a1.y);
            s[6] = (short)f2bf(a1.z); s[7] = (short)f2bf(a1.w);
            *(short8*)((char*)As + off) = s;
            *(short8*)((char*)Bs + off) = *(const short8*)(WT + (size_t)(col0 + r) * 256 + k0 + kc);
        }
        __syncthreads();
        #pragma unroll
        for (int kk = 0; kk < 64; kk += 32) {
            const int kbo = (kk + ((lane >> 4) << 3)) << 1;
            short8 af[2], bfr[2];
            #pragma unroll
            for (int i = 0; i < 2; ++i) {
                const int ra = wr + (i << 4) + (lane & 15);
                af[i]  = *(const short8*)((const char*)As + (((ra << 7) + kbo) ^ ((ra & 7) << 4)));
                const int rb = wc + (i << 4) + (lane & 15);
                bfr[i] = *(const short8*)((const char*)Bs + (((rb << 7) + kbo) ^ ((rb & 7) << 4)));
            }
            #pragma unroll
            for (int mi = 0; mi < 2; ++mi)
                #pragma unroll
                for (int ni = 0; ni < 2; ++ni)
                    acc[mi][ni] = __builtin_amdgcn_mfma_f32_16x16x32_bf16(af[mi], bfr[ni], acc[mi][ni], 0, 0, 0);
        }
        __syncthreads();
    }
}

// =================== mega: knn + KV-GEMM + Q-GEMM + zero(avg), role-interleaved ===================
// 2816 blocks = 256 groups x 11 roles: 0-3 knn | 4-7 KV | 8 Q | 9-10 zero
__global__ __launch_bounds__(256, 4)
void mega_kernel(const float* __restrict__ src, const float* __restrict__ tgt,
                 const float4* __restrict__ tgt4,
                 int* __restrict__ knn_idx,
                 const float* __restrict__ tgt_fea, const float* __restrict__ src_fea,
                 const u16* __restrict__ WTq, const u16* __restrict__ WTkv,
                 const float* __restrict__ bq, const float* __restrict__ bk,
                 const float* __restrict__ bv,
                 float* __restrict__ Qb, u16* __restrict__ Kbf, u16* __restrict__ Vbf,
                 float* __restrict__ avg)
{
    __shared__ u16 As[64 * 64];   // 8KB
    __shared__ u16 Bs[64 * 64];   // 8KB
    const int bid = blockIdx.x;
    const int t = threadIdx.x;
    const int lane = t & 63;
    const int lid = bid / 11;
    const int role = bid % 11;

    if (role < 4) {
        // ---- kNN v6: wave-per-query; register key[64] + branchless sorted cache-2;
        // pops rescan nothing; rare refill scans the REGISTER array (no loads).
        const int kb = lid * 4 + role;                 // 0..1023
        const int bn = (kb << 2) + (t >> 6);           // 0..4095
        const int b = bn >> 11;
        const float* sp = src + (size_t)bn * 3;
        const float px = sp[0], py = sp[1], pz = sp[2];
        const float x2 = px * px + py * py + pz * pz;
        const float4* t4 = tgt4 + (size_t)b * MM;
        unsigned key[64];
        unsigned s0 = 0xFFFFFFFFu, s1 = 0xFFFFFFFFu;   // two smallest unseen, sorted
        #pragma unroll
        for (int j = 0; j < 64; ++j) {
            const int m = (j << 6) + lane;
            const float4 tp = t4[m];
            const float dot = px * tp.x + py * tp.y + pz * tp.z;
            float d = (x2 + tp.w) - 2.0f * dot;
            d = d > 0.f ? d : 0.f;
            const unsigned k = ((unsigned)fminf(d * 32768.0f, 1048574.0f) << 12) | (unsigned)m;
            key[j] = k;
            const unsigned hi = k > s0 ? k : s0;       // insert into sorted cache-2
            s0 = k < s0 ? k : s0;
            s1 = hi < s1 ? hi : s1;
        }
        unsigned lastPop = 0, mykey = 0;
        for (int sel = 0; sel < 20; ++sel) {
            if (s0 == 0xFFFFFFFFu) {                   // rare (~0.3/query): register refill
                unsigned bst = 0xFFFFFFFFu;
                #pragma unroll
                for (int j = 0; j < 64; ++j) {
                    const unsigned k = key[j];
                    bst = (k > lastPop && k < bst) ? k : bst;
                }
                s0 = bst;
            }
            unsigned best = s0;
            #pragma unroll
            for (int s2 = 32; s2; s2 >>= 1) {
                const unsigned o = __shfl_xor(best, s2, 64);
                best = o < best ? o : best;
            }
            if (lane == sel) mykey = best;
            if (s0 == best) {                          // unique keys -> exactly one lane pops
                lastPop = s0;
                s0 = s1;
                s1 = 0xFFFFFFFFu;
            }
        }
        const int midx = (int)(mykey & 0xFFFu);
        const float* tb = tgt + (size_t)b * MM * 3;
        u64 ex = ~0ULL;
        if (lane < 20) {                               // exact f64 distance, np-order key
            const float* tp = tb + (size_t)midx * 3;
            const double pxd = px, pyd = py, pzd = pz;
            const double tx = tp[0], ty = tp[1], tz = tp[2];
            const double x2d = pxd * pxd + pyd * pyd + pzd * pzd;
            const double y2d = tx * tx + ty * ty + tz * tz;
            const double dtd = pxd * tx + pyd * ty + pzd * tz;
            double dd = (x2d + y2d) - 2.0 * dtd;
            dd = dd > 0.0 ? dd : 0.0;
            ex = (((u64)__double_as_longlong(dd)) & ~0xFFFULL) | (u64)midx;
        }
        int rank = 0;
        #pragma unroll
        for (int i = 0; i < 20; ++i) {
            const u64 o = __shfl(ex, i, 64);
            rank += (o < ex) ? 1 : 0;
        }
        if (lane < 20 && rank < 16)
            knn_idx[(size_t)bn * KNN + rank] = midx;
        return;
    }

    if (role < 8) {
        // ---- KV GEMM: [8192][512] = tgt_fea @ [WTk|WTv]^T, bf16 out, 64x64 tile
        const int kvb = lid * 4 + (role - 4);          // 0..1023
        const size_t row0 = (size_t)(kvb >> 3) * 64;
        const int col0 = (kvb & 7) * 64;
        f32x4 acc[2][2] = {};
        gemm64_body(tgt_fea, row0, WTkv, col0, As, Bs, t, acc);
        const int w = t >> 6;
        const int wr = (w >> 1) * 32, wc = (w & 1) * 32;
        const bool isv = col0 >= 256;
        u16* ob = isv ? Vbf : Kbf;
        const float* bs = isv ? bv : bk;
        const int cb = (isv ? col0 - 256 : col0) + wc;
        const int cq = lane & 15, rq = (lane >> 4) << 2;
        #pragma unroll
        for (int ni = 0; ni < 2; ++ni) {
            const int c = cb + (ni << 4) + cq;
            const float bval = bs[c];
            #pragma unroll
            for (int mi = 0; mi < 2; ++mi) {
                const size_t r = row0 + wr + (mi << 4) + rq;
                #pragma unroll
                for (int e = 0; e < 4; ++e)
                    ob[(r + e) * 256 + c] = f2bf(acc[mi][ni][e] + bval);
            }
        }
        return;
    }

    if (role == 8) {
        // ---- Q GEMM: [4096][256] f32 = src_fea @ WTq^T, 64x64 tile
        const int qb = lid;                            // 0..255
        const size_t row0 = (size_t)(qb >> 2) * 64;
        const int col0 = (qb & 3) * 64;
        f32x4 acc[2][2] = {};
        gemm64_body(src_fea, row0, WTq, col0, As, Bs, t, acc);
        const int w = t >> 6;
        const int wr = (w >> 1) * 32, wc = (w & 1) * 32;
        const int cq = lane & 15, rq = (lane >> 4) << 2;
        #pragma unroll
        for (int ni = 0; ni < 2; ++ni) {
            const int c = col0 + wc + (ni << 4) + cq;
            const float bval = bq[c];
            #pragma unroll
            for (int mi = 0; mi < 2; ++mi) {
                const size_t rbase = (row0 + wr + (mi << 4) + rq) * 256 + c;
                #pragma unroll
                for (int e = 0; e < 4; ++e)
                    Qb[rbase + (size_t)e * 256] = acc[mi][ni][e] + bval;
            }
        }
        return;
    }

    // ---- zero avg_attn: 16.78M f32 via f32x4
    {
        const int zb = lid * 2 + (role - 9);           // 0..511
        f32x4 z = {0.f, 0.f, 0.f, 0.f};
        f32x4* pz = (f32x4*)avg;
        const int base = zb * 256 + t;
        #pragma unroll
        for (int i = 0; i < 32; ++i)
            pz[base + i * 131072] = z;
    }
}

// =================== tail v2: attn + Wo1+LN+ReLU + Wo2 fused; 1024 blocks x 256 thr ===================
// Block owns 4 rows (4 waves, 1 query/wave). GEMMs: M=16 MFMA with Xs/Hs rows 4-15 zero-padded;
// each wave covers 64 cols = 4 strips of 16.
__global__ __launch_bounds__(256)
void tail_kernel(const float* __restrict__ Q, const u16* __restrict__ Kb,
                 const u16* __restrict__ Vb, const int* __restrict__ knn_idx,
                 const float* __restrict__ src_fea,
                 const u16* __restrict__ WTo1, const float* __restrict__ bo1,
                 const float* __restrict__ lng, const float* __restrict__ lnb,
                 const u16* __restrict__ WTo2, const float* __restrict__ bo2,
                 float* __restrict__ updated, float* __restrict__ avg_attn)
{
    __shared__ float q_sh[4][256];         // 4KB
    __shared__ float pw_sh[4][8][17];      // 2.2KB
    __shared__ int   idx_sh[4][16];        // 256B
    __shared__ u16   Xs[16 * 256];         // 8KB, XOR-swizzled rows; rows 4-15 zero
    __shared__ u16   Hs[16 * 256];         // 8KB, same
    __shared__ float2 red2[4][4];          // [wave][row] partial (s1,s2)
    const int t = threadIdx.x;
    const int w = t >> 6, lane = t & 63;
    const int r0 = blockIdx.x << 2;
    const int bn = r0 + w;
    const int b = bn >> 11;
    const int h = lane >> 3, k2 = lane & 7;

    {   // zero rows 4..15 of Xs and Hs (bytes [2048,8192) = u32 [512,2048))
        unsigned* xz = (unsigned*)Xs;
        unsigned* hz = (unsigned*)Hs;
        #pragma unroll
        for (int i = 0; i < 6; ++i) {
            xz[512 + t + i * 256] = 0u;
            hz[512 + t + i * 256] = 0u;
        }
    }

    // ---- attn: one query per wave (intra-wave LDS only; no barrier needed until Xs) ----
    *(float4*)&q_sh[w][lane << 2] = *(const float4*)(Q + (size_t)bn * 256 + (lane << 2));
    const int ia = knn_idx[(size_t)bn * KNN + k2];
    const int ib = knn_idx[(size_t)bn * KNN + 8 + k2];

    const u16* Ka = Kb + ((size_t)b * MM + ia) * 256 + h * DK;
    const u16* Kc = Kb + ((size_t)b * MM + ib) * 256 + h * DK;
    const float* qh = &q_sh[w][h * DK];
    float s0 = 0.f, s1 = 0.f;
    #pragma unroll
    for (int j = 0; j < DK; j += 8) {
        const short8 ka = *(const short8*)(Ka + j);
        const short8 kc = *(const short8*)(Kc + j);
        #pragma unroll
        for (int e = 0; e < 8; ++e) {
            const float qv = qh[j + e];
            s0 = fmaf(qv, bf2f((u16)ka[e]), s0);
            s1 = fmaf(qv, bf2f((u16)kc[e]), s1);
        }
    }
    s0 *= 0.17677669529663688f;
    s1 *= 0.17677669529663688f;

    float mx = fmaxf(s0, s1);
    mx = fmaxf(mx, __shfl_xor(mx, 1, 64));
    mx = fmaxf(mx, __shfl_xor(mx, 2, 64));
    mx = fmaxf(mx, __shfl_xor(mx, 4, 64));
    const float e0 = expf(s0 - mx), e1 = expf(s1 - mx);
    float sum = e0 + e1;
    sum += __shfl_xor(sum, 1, 64);
    sum += __shfl_xor(sum, 2, 64);
    sum += __shfl_xor(sum, 4, 64);
    const float inv = 1.0f / sum;
    const float p0 = e0 * inv, p1 = e1 * inv;

    float a0 = p0, a1 = p1;
    a0 += __shfl_xor(a0, 8, 64);  a1 += __shfl_xor(a1, 8, 64);
    a0 += __shfl_xor(a0, 16, 64); a1 += __shfl_xor(a1, 16, 64);
    a0 += __shfl_xor(a0, 32, 64); a1 += __shfl_xor(a1, 32, 64);
    if (h == 0) {
        avg_attn[(size_t)bn * MM + ia] = a0 * 0.125f;
        avg_attn[(size_t)bn * MM + ib] = a1 * 0.125f;
        idx_sh[w][k2] = ia;
        idx_sh[w][8 + k2] = ib;
    }
    pw_sh[w][h][k2] = p0;
    pw_sh[w][h][8 + k2] = p1;

    {   // PV + residual -> Xs row w (bf16, swizzled)
        const int d0 = lane << 2;
        const int h2 = lane >> 3;
        float o0 = 0.f, o1 = 0.f, o2 = 0.f, o3 = 0.f;
        #pragma unroll
        for (int k = 0; k < KNN; ++k) {
            const float p = pw_sh[w][h2][k];
            const int ik = idx_sh[w][k];
            const short4v v4 = *(const short4v*)(Vb + ((size_t)b * MM + ik) * 256 + d0);
            o0 = fmaf(p, bf2f((u16)v4[0]), o0);
            o1 = fmaf(p, bf2f((u16)v4[1]), o1);
            o2 = fmaf(p, bf2f((u16)v4[2]), o2);
            o3 = fmaf(p, bf2f((u16)v4[3]), o3);
        }
        const float4 sf = *(const float4*)(src_fea + (size_t)bn * 256 + d0);
        short4v xo;
        xo[0] = (short)f2bf(o0 + sf.x);
        xo[1] = (short)f2bf(o1 + sf.y);
        xo[2] = (short)f2bf(o2 + sf.z);
        xo[3] = (short)f2bf(o3 + sf.w);
        const int off = ((w << 9) + (d0 << 1)) ^ ((w & 7) << 4);
        *(short4v*)((char*)Xs + off) = xo;
    }
    __syncthreads();

    // ---- Wo1 (M=16, rows 4-15 zero) + bias; wave covers 64 cols = 4 strips ----
    const int cq = lane & 15, ks = lane >> 4;
    f32x4 acc1[4] = {};
    #pragma unroll
    for (int s = 0; s < 4; ++s) {
        const int colB = (w << 6) + (s << 4) + cq;
        const u16* bp = WTo1 + (size_t)colB * 256;
        #pragma unroll
        for (int kk = 0; kk < 256; kk += 32) {
            const int k8 = kk + (ks << 3);
            const short8 af = *(const short8*)((const char*)Xs + (((cq << 9) + (k8 << 1)) ^ ((cq & 7) << 4)));
            const short8 bfrg = *(const short8*)(bp + k8);
            acc1[s] = __builtin_amdgcn_mfma_f32_16x16x32_bf16(af, bfrg, acc1[s], 0, 0, 0);
        }
        const float bval = bo1[colB];
        #pragma unroll
        for (int e = 0; e < 4; ++e) acc1[s][e] += bval;
    }
    {   // per-row (rows 0-3, ks==0 lanes) partial sums over this wave's 64 cols
        #pragma unroll
        for (int e = 0; e < 4; ++e) {
            float v = acc1[0][e] + acc1[1][e] + acc1[2][e] + acc1[3][e];
            float vv = acc1[0][e]*acc1[0][e] + acc1[1][e]*acc1[1][e]
                     + acc1[2][e]*acc1[2][e] + acc1[3][e]*acc1[3][e];
            v += __shfl_xor(v, 1, 64); vv += __shfl_xor(vv, 1, 64);
            v += __shfl_xor(v, 2, 64); vv += __shfl_xor(vv, 2, 64);
            v += __shfl_xor(v, 4, 64); vv += __shfl_xor(vv, 4, 64);
            v += __shfl_xor(v, 8, 64); vv += __shfl_xor(vv, 8, 64);
            if (ks == 0 && cq == 0) {
                float2 pr; pr.x = v; pr.y = vv;
                red2[w][e] = pr;
            }
        }
    }
    __syncthreads();
    if (ks == 0) {  // LN + ReLU -> Hs rows 0-3
        float g4[4], b4[4];
        #pragma unroll
        for (int s = 0; s < 4; ++s) {
            const int colB = (w << 6) + (s << 4) + cq;
            g4[s] = lng[colB]; b4[s] = lnb[colB];
        }
        #pragma unroll
        for (int e = 0; e < 4; ++e) {
            float S1 = 0.f, S2 = 0.f;
            #pragma unroll
            for (int w2 = 0; w2 < 4; ++w2) {
                const float2 pr = red2[w2][e];
                S1 += pr.x; S2 += pr.y;
            }
            const float mean = S1 * (1.0f / 256.0f);
            const float var = S2 * (1.0f / 256.0f) - mean * mean;
            const float rstd = 1.0f / sqrtf(var + 1e-5f);
            #pragma unroll
            for (int s = 0; s < 4; ++s) {
                const int colB = (w << 6) + (s << 4) + cq;
                const float y = (acc1[s][e] - mean) * rstd * g4[s] + b4[s];
                const int off = ((e << 9) + (colB << 1)) ^ ((e & 7) << 4);
                *(u16*)((char*)Hs + off) = f2bf(fmaxf(y, 0.0f));
            }
        }
    }
    __syncthreads();

    // ---- Wo2 (M=16, rows 4-15 zero) -> updated rows r0..r0+3 ----
    #pragma unroll
    for (int s = 0; s < 4; ++s) {
        const int colB = (w << 6) + (s << 4) + cq;
        const u16* bp = WTo2 + (size_t)colB * 256;
        f32x4 acc2 = {};
        #pragma unroll
        for (int kk = 0; kk < 256; kk += 32) {
            const int k8 = kk + (ks << 3);
            const short8 af = *(const short8*)((const char*)Hs + (((cq << 9) + (k8 << 1)) ^ ((cq & 7) << 4)));
            const short8 bfrg = *(const short8*)(bp + k8);
            acc2 = __builtin_amdgcn_mfma_f32_16x16x32_bf16(af, bfrg, acc2, 0, 0, 0);
        }
        if (ks == 0) {
            const float bval = bo2[colB];
            #pragma unroll
            for (int e = 0; e < 4; ++e)
                updated[(size_t)(r0 + e) * 256 + colB] = acc2[e] + bval;
        }
    }
}

extern "C" void kernel_launch(void* const* d_in, const int* in_sizes, int n_in,
                              void* d_out, int out_size, void* d_ws, size_t ws_size,
                              hipStream_t stream) {
    const float* src     = (const float*)d_in[0];
    const float* tgt     = (const float*)d_in[1];
    const float* src_fea = (const float*)d_in[2];
    const float* tgt_fea = (const float*)d_in[3];
    const float* Wq  = (const float*)d_in[4];   const float* bq  = (const float*)d_in[5];
    const float* Wk  = (const float*)d_in[6];   const float* bk  = (const float*)d_in[7];
    const float* Wv  = (const float*)d_in[8];   const float* bv  = (const float*)d_in[9];
    const float* Wo1 = (const float*)d_in[10];  const float* bo1 = (const float*)d_in[11];
    const float* lng = (const float*)d_in[12];  const float* lnb = (const float*)d_in[13];
    const float* Wo2 = (const float*)d_in[14];  const float* bo2 = (const float*)d_in[15];
    (void)in_sizes; (void)n_in; (void)out_size; (void)ws_size;

    float* out     = (float*)d_out;
    float* updated = out;                                   // [B,N,D] f32
    float* avg     = out + (size_t)BB * NN * DD;            // [B,N,M] f32

    char* p = (char*)d_ws;
    u16* WTq  = (u16*)p;   p += 256 * 256 * 2;
    u16* WTk  = (u16*)p;   p += 256 * 256 * 2;              // WTk|WTv contiguous = WTkv
    u16* WTv  = (u16*)p;   p += 256 * 256 * 2;
    u16* WTo1 = (u16*)p;   p += 256 * 256 * 2;
    u16* WTo2 = (u16*)p;   p += 256 * 256 * 2;
    float* Qb = (float*)p; p += (size_t)BB * NN * DD * 4;   // 4MB
    u16* Kbf  = (u16*)p;   p += (size_t)BB * MM * DD * 2;   // 4MB
    u16* Vbf  = (u16*)p;   p += (size_t)BB * MM * DD * 2;   // 4MB
    int* knn  = (int*)p;   p += (size_t)BB * NN * KNN * 4;  // 256KB
    float4* tgt4 = (float4*)p; p += (size_t)BB * MM * 16;   // 128KB

    dim3 blk(256);
    prep<<<112, blk, 0, stream>>>(Wq, Wk, Wv, Wo1, Wo2, WTq, WTk, WTv, WTo1, WTo2,
                                  tgt, tgt4);
    mega_kernel<<<2816, blk, 0, stream>>>(src, tgt, tgt4, knn, tgt_fea, src_fea, WTq, WTk,
                                          bq, bk, bv, Qb, Kbf, Vbf, avg);
    tail_kernel<<<1024, blk, 0, stream>>>(Qb, Kbf, Vbf, knn, src_fea,
                                          WTo1, bo1, lng, lnb, WTo2, bo2,
                                          updated, avg);
}

// Round 11
// 167.543 us; speedup vs baseline: 1.4450x; 1.1008x over previous
//
#include <hip/hip_runtime.h>
#include <math.h>

#define BB 2
#define NN 2048
#define MM 4096
#define DD 256
#define HH 8
#define DK 32
#define KNN 16

typedef __attribute__((ext_vector_type(8))) short short8;
typedef __attribute__((ext_vector_type(4))) short short4v;
typedef __attribute__((ext_vector_type(4))) float f32x4;
typedef unsigned long long u64;
typedef unsigned short u16;

static __device__ __forceinline__ u16 f2bf(float f) {
    union { float f; unsigned u; } v; v.f = f;
    unsigned r = v.u + 0x7FFF + ((v.u >> 16) & 1);   // round-to-nearest-even
    return (u16)(r >> 16);
}
static __device__ __forceinline__ float bf2f(u16 u) {
    union { unsigned u; float f; } v; v.u = ((unsigned)u) << 16;
    return v.f;
}

// =================== prep: weight transpose+cvt (blocks 0-79) + tgt4 pack (blocks 80-111) ===================
__global__ __launch_bounds__(256)
void prep(const float* W0, const float* W1, const float* W2, const float* W3, const float* W4,
          u16* O0, u16* O1, u16* O2, u16* O3, u16* O4,
          const float* __restrict__ tgt, float4* __restrict__ tgt4)
{
    __shared__ float tile[64][65];
    const int bid = blockIdx.x;
    const int t = threadIdx.x;
    if (bid >= 80) {                         // pack tgt -> (x,y,z,|y|^2)
        const int i = (bid - 80) * 256 + t;  // 0..8191
        const float x = tgt[i * 3 + 0], y = tgt[i * 3 + 1], z = tgt[i * 3 + 2];
        float4 o; o.x = x; o.y = y; o.z = z; o.w = x * x + y * y + z * z;
        tgt4[i] = o;
        return;
    }
    const int m = bid >> 4, tl = bid & 15;
    const int tr = (tl >> 2) * 64, tc = (tl & 3) * 64;
    const float* W = m == 0 ? W0 : m == 1 ? W1 : m == 2 ? W2 : m == 3 ? W3 : W4;
    u16*        O = m == 0 ? O0 : m == 1 ? O1 : m == 2 ? O2 : m == 3 ? O3 : O4;
    const int c = t & 63, r4 = t >> 6;
    #pragma unroll
    for (int i = 0; i < 16; ++i) {
        const int r = (r4 << 4) + i;
        tile[r][c] = W[(size_t)(tr + r) * 256 + tc + c];
    }
    __syncthreads();
    #pragma unroll
    for (int i = 0; i < 16; ++i) {
        const int cc = (r4 << 4) + i;
        O[(size_t)(tc + cc) * 256 + tr + c] = f2bf(tile[c][cc]);
    }
}

// =================== mega: knn + KV-GEMM(64x128) + Q-GEMM(64x64) + zero(avg) ===================
// 2304 blocks = 256 groups x 9 roles: 0-3 knn | 4-5 KV | 6 Q | 7-8 zero
__global__ __launch_bounds__(256, 4)
void mega_kernel(const float* __restrict__ src, const float* __restrict__ tgt,
                 const float4* __restrict__ tgt4,
                 int* __restrict__ knn_idx,
                 const float* __restrict__ tgt_fea, const float* __restrict__ src_fea,
                 const u16* __restrict__ WTq, const u16* __restrict__ WTkv,
                 const float* __restrict__ bq, const float* __restrict__ bk,
                 const float* __restrict__ bv,
                 float* __restrict__ Qb, u16* __restrict__ Kbf, u16* __restrict__ Vbf,
                 float* __restrict__ avg)
{
    __shared__ u16 As[64 * 64];    // 8KB
    __shared__ u16 Bs[128 * 64];   // 16KB
    const int bid = blockIdx.x;
    const int t = threadIdx.x;
    const int lane = t & 63;
    const int lid = bid / 9;
    const int role = bid % 9;

    if (role < 4) {
        // ---- kNN v6 (proven R10): register key[64] + branchless sorted cache-2.
        const int kb = lid * 4 + role;                 // 0..1023
        const int bn = (kb << 2) + (t >> 6);           // 0..4095
        const int b = bn >> 11;
        const float* sp = src + (size_t)bn * 3;
        const float px = sp[0], py = sp[1], pz = sp[2];
        const float x2 = px * px + py * py + pz * pz;
        const float4* t4 = tgt4 + (size_t)b * MM;
        unsigned key[64];
        unsigned s0 = 0xFFFFFFFFu, s1 = 0xFFFFFFFFu;
        #pragma unroll
        for (int j = 0; j < 64; ++j) {
            const int m = (j << 6) + lane;
            const float4 tp = t4[m];
            const float dot = px * tp.x + py * tp.y + pz * tp.z;
            float d = (x2 + tp.w) - 2.0f * dot;
            d = d > 0.f ? d : 0.f;
            const unsigned k = ((unsigned)fminf(d * 32768.0f, 1048574.0f) << 12) | (unsigned)m;
            key[j] = k;
            const unsigned hi = k > s0 ? k : s0;
            s0 = k < s0 ? k : s0;
            s1 = hi < s1 ? hi : s1;
        }
        unsigned lastPop = 0, mykey = 0;
        for (int sel = 0; sel < 20; ++sel) {
            if (s0 == 0xFFFFFFFFu) {                   // rare register refill
                unsigned bst = 0xFFFFFFFFu;
                #pragma unroll
                for (int j = 0; j < 64; ++j) {
                    const unsigned k = key[j];
                    bst = (k > lastPop && k < bst) ? k : bst;
                }
                s0 = bst;
            }
            unsigned best = s0;
            #pragma unroll
            for (int s2 = 32; s2; s2 >>= 1) {
                const unsigned o = __shfl_xor(best, s2, 64);
                best = o < best ? o : best;
            }
            if (lane == sel) mykey = best;
            if (s0 == best) {
                lastPop = s0;
                s0 = s1;
                s1 = 0xFFFFFFFFu;
            }
        }
        const int midx = (int)(mykey & 0xFFFu);
        const float* tb = tgt + (size_t)b * MM * 3;
        u64 ex = ~0ULL;
        if (lane < 20) {                               // exact f64 re-rank, np tie-break
            const float* tp = tb + (size_t)midx * 3;
            const double pxd = px, pyd = py, pzd = pz;
            const double tx = tp[0], ty = tp[1], tz = tp[2];
            const double x2d = pxd * pxd + pyd * pyd + pzd * pzd;
            const double y2d = tx * tx + ty * ty + tz * tz;
            const double dtd = pxd * tx + pyd * ty + pzd * tz;
            double dd = (x2d + y2d) - 2.0 * dtd;
            dd = dd > 0.0 ? dd : 0.0;
            ex = (((u64)__double_as_longlong(dd)) & ~0xFFFULL) | (u64)midx;
        }
        int rank = 0;
        #pragma unroll
        for (int i = 0; i < 20; ++i) {
            const u64 o = __shfl(ex, i, 64);
            rank += (o < ex) ? 1 : 0;
        }
        if (lane < 20 && rank < 16)
            knn_idx[(size_t)bn * KNN + rank] = midx;
        return;
    }

    if (role < 6) {
        // ---- KV GEMM: [8192][512] = tgt_fea @ [WTk|WTv]^T, 64x128 tile, bf16 out
        const int kvb = lid * 2 + (role - 4);          // 0..511
        const size_t row0 = (size_t)(kvb >> 2) * 64;   // 128 row tiles
        const int col0 = (kvb & 3) * 128;              // 4 col tiles
        const int w = t >> 6;
        const int wr = (w >> 1) * 32, wc = (w & 1) * 64;
        f32x4 acc[2][4] = {};
        for (int k0 = 0; k0 < 256; k0 += 64) {
            #pragma unroll
            for (int e = 0; e < 2; ++e) {              // stage A (f32 -> bf16)
                const int flat = t + (e << 8);
                const int r = flat >> 3, kc = (flat & 7) << 3;
                const int off = ((r << 7) + (kc << 1)) ^ ((r & 7) << 4);
                const float* ap = tgt_fea + (row0 + r) * 256 + k0 + kc;
                float4 a0 = *(const float4*)ap;
                float4 a1 = *(const float4*)(ap + 4);
                short8 s;
                s[0] = (short)f2bf(a0.x); s[1] = (short)f2bf(a0.y);
                s[2] = (short)f2bf(a0.z); s[3] = (short)f2bf(a0.w);
                s[4] = (short)f2bf(a1.x); s[5] = (short)f2bf(a1.y);
                s[6] = (short)f2bf(a1.z); s[7] = (short)f2bf(a1.w);
                *(short8*)((char*)As + off) = s;
            }
            #pragma unroll
            for (int e = 0; e < 4; ++e) {              // stage B (bf16 copy)
                const int flat = t + (e << 8);
                const int r = flat >> 3, kc = (flat & 7) << 3;
                const int off = ((r << 7) + (kc << 1)) ^ ((r & 7) << 4);
                *(short8*)((char*)Bs + off) = *(const short8*)(WTkv + (size_t)(col0 + r) * 256 + k0 + kc);
            }
            __syncthreads();
            #pragma unroll
            for (int kk = 0; kk < 64; kk += 32) {
                const int kbo = (kk + ((lane >> 4) << 3)) << 1;
                short8 af[2], bfr[4];
                #pragma unroll
                for (int i = 0; i < 2; ++i) {
                    const int ra = wr + (i << 4) + (lane & 15);
                    af[i] = *(const short8*)((const char*)As + (((ra << 7) + kbo) ^ ((ra & 7) << 4)));
                }
                #pragma unroll
                for (int i = 0; i < 4; ++i) {
                    const int rb = wc + (i << 4) + (lane & 15);
                    bfr[i] = *(const short8*)((const char*)Bs + (((rb << 7) + kbo) ^ ((rb & 7) << 4)));
                }
                #pragma unroll
                for (int mi = 0; mi < 2; ++mi)
                    #pragma unroll
                    for (int ni = 0; ni < 4; ++ni)
                        acc[mi][ni] = __builtin_amdgcn_mfma_f32_16x16x32_bf16(af[mi], bfr[ni], acc[mi][ni], 0, 0, 0);
            }
            __syncthreads();
        }
        const bool isv = col0 >= 256;
        u16* ob = isv ? Vbf : Kbf;
        const float* bs = isv ? bv : bk;
        const int cb = (isv ? col0 - 256 : col0) + wc;
        const int cq = lane & 15, rq = (lane >> 4) << 2;
        #pragma unroll
        for (int ni = 0; ni < 4; ++ni) {
            const int c = cb + (ni << 4) + cq;
            const float bval = bs[c];
            #pragma unroll
            for (int mi = 0; mi < 2; ++mi) {
                const size_t r = row0 + wr + (mi << 4) + rq;
                #pragma unroll
                for (int e = 0; e < 4; ++e)
                    ob[(r + e) * 256 + c] = f2bf(acc[mi][ni][e] + bval);
            }
        }
        return;
    }

    if (role == 6) {
        // ---- Q GEMM: [4096][256] f32 = src_fea @ WTq^T, 64x64 tile
        const int qb = lid;                            // 0..255
        const size_t row0 = (size_t)(qb >> 2) * 64;
        const int col0 = (qb & 3) * 64;
        const int w = t >> 6;
        const int wr = (w >> 1) * 32, wc = (w & 1) * 32;
        f32x4 acc[2][2] = {};
        for (int k0 = 0; k0 < 256; k0 += 64) {
            #pragma unroll
            for (int e = 0; e < 2; ++e) {
                const int flat = t + (e << 8);
                const int r = flat >> 3, kc = (flat & 7) << 3;
                const int off = ((r << 7) + (kc << 1)) ^ ((r & 7) << 4);
                const float* ap = src_fea + (row0 + r) * 256 + k0 + kc;
                float4 a0 = *(const float4*)ap;
                float4 a1 = *(const float4*)(ap + 4);
                short8 s;
                s[0] = (short)f2bf(a0.x); s[1] = (short)f2bf(a0.y);
                s[2] = (short)f2bf(a0.z); s[3] = (short)f2bf(a0.w);
                s[4] = (short)f2bf(a1.x); s[5] = (short)f2bf(a1.y);
                s[6] = (short)f2bf(a1.z); s[7] = (short)f2bf(a1.w);
                *(short8*)((char*)As + off) = s;
                *(short8*)((char*)Bs + off) = *(const short8*)(WTq + (size_t)(col0 + r) * 256 + k0 + kc);
            }
            __syncthreads();
            #pragma unroll
            for (int kk = 0; kk < 64; kk += 32) {
                const int kbo = (kk + ((lane >> 4) << 3)) << 1;
                short8 af[2], bfr[2];
                #pragma unroll
                for (int i = 0; i < 2; ++i) {
                    const int ra = wr + (i << 4) + (lane & 15);
                    af[i]  = *(const short8*)((const char*)As + (((ra << 7) + kbo) ^ ((ra & 7) << 4)));
                    const int rb = wc + (i << 4) + (lane & 15);
                    bfr[i] = *(const short8*)((const char*)Bs + (((rb << 7) + kbo) ^ ((rb & 7) << 4)));
                }
                #pragma unroll
                for (int mi = 0; mi < 2; ++mi)
                    #pragma unroll
                    for (int ni = 0; ni < 2; ++ni)
                        acc[mi][ni] = __builtin_amdgcn_mfma_f32_16x16x32_bf16(af[mi], bfr[ni], acc[mi][ni], 0, 0, 0);
            }
            __syncthreads();
        }
        const int cq = lane & 15, rq = (lane >> 4) << 2;
        #pragma unroll
        for (int ni = 0; ni < 2; ++ni) {
            const int c = col0 + wc + (ni << 4) + cq;
            const float bval = bq[c];
            #pragma unroll
            for (int mi = 0; mi < 2; ++mi) {
                const size_t rbase = (row0 + wr + (mi << 4) + rq) * 256 + c;
                #pragma unroll
                for (int e = 0; e < 4; ++e)
                    Qb[rbase + (size_t)e * 256] = acc[mi][ni][e] + bval;
            }
        }
        return;
    }

    // ---- zero avg_attn: 16.78M f32 via f32x4
    {
        const int zb = lid * 2 + (role - 7);           // 0..511
        f32x4 z = {0.f, 0.f, 0.f, 0.f};
        f32x4* pz = (f32x4*)avg;
        const int base = zb * 256 + t;
        #pragma unroll
        for (int i = 0; i < 32; ++i)
            pz[base + i * 131072] = z;
    }
}

// =================== tail v3: attn + Wo1+LN+ReLU + Wo2 fused; 512 blocks x 512 thr ===================
// Block owns 8 rows (8 waves, 1 query/wave). M=16 MFMA with Xs/Hs rows 8-15 zero-padded;
// each wave covers 32 cols = 2 strips of 16.
__global__ __launch_bounds__(512)
void tail_kernel(const float* __restrict__ Q, const u16* __restrict__ Kb,
                 const u16* __restrict__ Vb, const int* __restrict__ knn_idx,
                 const float* __restrict__ src_fea,
                 const u16* __restrict__ WTo1, const float* __restrict__ bo1,
                 const float* __restrict__ lng, const float* __restrict__ lnb,
                 const u16* __restrict__ WTo2, const float* __restrict__ bo2,
                 float* __restrict__ updated, float* __restrict__ avg_attn)
{
    __shared__ float q_sh[8][256];         // 8KB
    __shared__ float pw_sh[8][8][17];      // 4.4KB
    __shared__ int   idx_sh[8][16];        // 512B
    __shared__ u16   Xs[16 * 256];         // 8KB, XOR-swizzled rows; rows 8-15 zero
    __shared__ u16   Hs[16 * 256];         // 8KB, same
    __shared__ float2 red2[8][8];          // [wave][row] partial (s1,s2)
    const int t = threadIdx.x;
    const int w = t >> 6, lane = t & 63;
    const int r0 = blockIdx.x << 3;
    const int bn = r0 + w;
    const int b = bn >> 11;
    const int h = lane >> 3, k2 = lane & 7;

    {   // zero rows 8..15 of Xs and Hs (bytes [4096,8192) = u32 [1024,2048))
        unsigned* xz = (unsigned*)Xs;
        unsigned* hz = (unsigned*)Hs;
        #pragma unroll
        for (int i = 0; i < 2; ++i) {
            xz[1024 + t + i * 512] = 0u;
            hz[1024 + t + i * 512] = 0u;
        }
    }

    // ---- attn: one query per wave (intra-wave only until Xs barrier) ----
    *(float4*)&q_sh[w][lane << 2] = *(const float4*)(Q + (size_t)bn * 256 + (lane << 2));
    const int ia = knn_idx[(size_t)bn * KNN + k2];
    const int ib = knn_idx[(size_t)bn * KNN + 8 + k2];

    const u16* Ka = Kb + ((size_t)b * MM + ia) * 256 + h * DK;
    const u16* Kc = Kb + ((size_t)b * MM + ib) * 256 + h * DK;
    const float* qh = &q_sh[w][h * DK];
    float s0 = 0.f, s1 = 0.f;
    #pragma unroll
    for (int j = 0; j < DK; j += 8) {
        const short8 ka = *(const short8*)(Ka + j);
        const short8 kc = *(const short8*)(Kc + j);
        #pragma unroll
        for (int e = 0; e < 8; ++e) {
            const float qv = qh[j + e];
            s0 = fmaf(qv, bf2f((u16)ka[e]), s0);
            s1 = fmaf(qv, bf2f((u16)kc[e]), s1);
        }
    }
    s0 *= 0.17677669529663688f;
    s1 *= 0.17677669529663688f;

    float mx = fmaxf(s0, s1);
    mx = fmaxf(mx, __shfl_xor(mx, 1, 64));
    mx = fmaxf(mx, __shfl_xor(mx, 2, 64));
    mx = fmaxf(mx, __shfl_xor(mx, 4, 64));
    const float e0 = expf(s0 - mx), e1 = expf(s1 - mx);
    float sum = e0 + e1;
    sum += __shfl_xor(sum, 1, 64);
    sum += __shfl_xor(sum, 2, 64);
    sum += __shfl_xor(sum, 4, 64);
    const float inv = 1.0f / sum;
    const float p0 = e0 * inv, p1 = e1 * inv;

    float a0 = p0, a1 = p1;
    a0 += __shfl_xor(a0, 8, 64);  a1 += __shfl_xor(a1, 8, 64);
    a0 += __shfl_xor(a0, 16, 64); a1 += __shfl_xor(a1, 16, 64);
    a0 += __shfl_xor(a0, 32, 64); a1 += __shfl_xor(a1, 32, 64);
    if (h == 0) {
        avg_attn[(size_t)bn * MM + ia] = a0 * 0.125f;
        avg_attn[(size_t)bn * MM + ib] = a1 * 0.125f;
        idx_sh[w][k2] = ia;
        idx_sh[w][8 + k2] = ib;
    }
    pw_sh[w][h][k2] = p0;
    pw_sh[w][h][8 + k2] = p1;

    {   // PV + residual -> Xs row w (bf16, swizzled)
        const int d0 = lane << 2;
        const int h2 = lane >> 3;
        float o0 = 0.f, o1 = 0.f, o2 = 0.f, o3 = 0.f;
        #pragma unroll
        for (int k = 0; k < KNN; ++k) {
            const float p = pw_sh[w][h2][k];
            const int ik = idx_sh[w][k];
            const short4v v4 = *(const short4v*)(Vb + ((size_t)b * MM + ik) * 256 + d0);
            o0 = fmaf(p, bf2f((u16)v4[0]), o0);
            o1 = fmaf(p, bf2f((u16)v4[1]), o1);
            o2 = fmaf(p, bf2f((u16)v4[2]), o2);
            o3 = fmaf(p, bf2f((u16)v4[3]), o3);
        }
        const float4 sf = *(const float4*)(src_fea + (size_t)bn * 256 + d0);
        short4v xo;
        xo[0] = (short)f2bf(o0 + sf.x);
        xo[1] = (short)f2bf(o1 + sf.y);
        xo[2] = (short)f2bf(o2 + sf.z);
        xo[3] = (short)f2bf(o3 + sf.w);
        const int off = ((w << 9) + (d0 << 1)) ^ ((w & 7) << 4);
        *(short4v*)((char*)Xs + off) = xo;
    }
    __syncthreads();

    // ---- Wo1 (M=16, rows 8-15 zero) + bias; wave covers 32 cols = 2 strips ----
    const int cq = lane & 15, ks = lane >> 4;          // ks 0..3 = K-slice
    f32x4 acc1[2] = {};
    #pragma unroll
    for (int s = 0; s < 2; ++s) {
        const int colB = (w << 5) + (s << 4) + cq;
        const u16* bp = WTo1 + (size_t)colB * 256;
        #pragma unroll
        for (int kk = 0; kk < 256; kk += 32) {
            const int k8 = kk + (ks << 3);
            const short8 af = *(const short8*)((const char*)Xs + (((cq << 9) + (k8 << 1)) ^ ((cq & 7) << 4)));
            const short8 bfrg = *(const short8*)(bp + k8);
            acc1[s] = __builtin_amdgcn_mfma_f32_16x16x32_bf16(af, bfrg, acc1[s], 0, 0, 0);
        }
        const float bval = bo1[colB];
        #pragma unroll
        for (int e = 0; e < 4; ++e) acc1[s][e] += bval;
    }
    {   // per-row partial sums over this wave's 32 cols; rows 0-7 live in ks=0,1 lanes
        #pragma unroll
        for (int e = 0; e < 4; ++e) {
            float v  = acc1[0][e] + acc1[1][e];
            float vv = acc1[0][e]*acc1[0][e] + acc1[1][e]*acc1[1][e];
            v += __shfl_xor(v, 1, 64); vv += __shfl_xor(vv, 1, 64);
            v += __shfl_xor(v, 2, 64); vv += __shfl_xor(vv, 2, 64);
            v += __shfl_xor(v, 4, 64); vv += __shfl_xor(vv, 4, 64);
            v += __shfl_xor(v, 8, 64); vv += __shfl_xor(vv, 8, 64);
            if (cq == 0 && ks < 2) {
                float2 pr; pr.x = v; pr.y = vv;
                red2[w][(ks << 2) + e] = pr;
            }
        }
    }
    __syncthreads();
    if (ks < 2) {   // LN + ReLU -> Hs rows 0-7
        float g2[2], b2[2];
        #pragma unroll
        for (int s = 0; s < 2; ++s) {
            const int colB = (w << 5) + (s << 4) + cq;
            g2[s] = lng[colB]; b2[s] = lnb[colB];
        }
        #pragma unroll
        for (int e = 0; e < 4; ++e) {
            const int r = (ks << 2) + e;
            float S1 = 0.f, S2 = 0.f;
            #pragma unroll
            for (int w2 = 0; w2 < 8; ++w2) {
                const float2 pr = red2[w2][r];
                S1 += pr.x; S2 += pr.y;
            }
            const float mean = S1 * (1.0f / 256.0f);
            const float var = S2 * (1.0f / 256.0f) - mean * mean;
            const float rstd = 1.0f / sqrtf(var + 1e-5f);
            #pragma unroll
            for (int s = 0; s < 2; ++s) {
                const int colB = (w << 5) + (s << 4) + cq;
                const float y = (acc1[s][e] - mean) * rstd * g2[s] + b2[s];
                const int off = ((r << 9) + (colB << 1)) ^ ((r & 7) << 4);
                *(u16*)((char*)Hs + off) = f2bf(fmaxf(y, 0.0f));
            }
        }
    }
    __syncthreads();

    // ---- Wo2 (M=16, rows 8-15 zero) -> updated rows r0..r0+7 ----
    #pragma unroll
    for (int s = 0; s < 2; ++s) {
        const int colB = (w << 5) + (s << 4) + cq;
        const u16* bp = WTo2 + (size_t)colB * 256;
        f32x4 acc2 = {};
        #pragma unroll
        for (int kk = 0; kk < 256; kk += 32) {
            const int k8 = kk + (ks << 3);
            const short8 af = *(const short8*)((const char*)Hs + (((cq << 9) + (k8 << 1)) ^ ((cq & 7) << 4)));
            const short8 bfrg = *(const short8*)(bp + k8);
            acc2 = __builtin_amdgcn_mfma_f32_16x16x32_bf16(af, bfrg, acc2, 0, 0, 0);
        }
        if (ks < 2) {
            const float bval = bo2[colB];
            #pragma unroll
            for (int e = 0; e < 4; ++e)
                updated[(size_t)(r0 + (ks << 2) + e) * 256 + colB] = acc2[e] + bval;
        }
    }
}

extern "C" void kernel_launch(void* const* d_in, const int* in_sizes, int n_in,
                              void* d_out, int out_size, void* d_ws, size_t ws_size,
                              hipStream_t stream) {
    const float* src     = (const float*)d_in[0];
    const float* tgt     = (const float*)d_in[1];
    const float* src_fea = (const float*)d_in[2];
    const float* tgt_fea = (const float*)d_in[3];
    const float* Wq  = (const float*)d_in[4];   const float* bq  = (const float*)d_in[5];
    const float* Wk  = (const float*)d_in[6];   const float* bk  = (const float*)d_in[7];
    const float* Wv  = (const float*)d_in[8];   const float* bv  = (const float*)d_in[9];
    const float* Wo1 = (const float*)d_in[10];  const float* bo1 = (const float*)d_in[11];
    const float* lng = (const float*)d_in[12];  const float* lnb = (const float*)d_in[13];
    const float* Wo2 = (const float*)d_in[14];  const float* bo2 = (const float*)d_in[15];
    (void)in_sizes; (void)n_in; (void)out_size; (void)ws_size;

    float* out     = (float*)d_out;
    float* updated = out;                                   // [B,N,D] f32
    float* avg     = out + (size_t)BB * NN * DD;            // [B,N,M] f32

    char* p = (char*)d_ws;
    u16* WTq  = (u16*)p;   p += 256 * 256 * 2;
    u16* WTk  = (u16*)p;   p += 256 * 256 * 2;              // WTk|WTv contiguous = WTkv
    u16* WTv  = (u16*)p;   p += 256 * 256 * 2;
    u16* WTo1 = (u16*)p;   p += 256 * 256 * 2;
    u16* WTo2 = (u16*)p;   p += 256 * 256 * 2;
    float* Qb = (float*)p; p += (size_t)BB * NN * DD * 4;   // 4MB
    u16* Kbf  = (u16*)p;   p += (size_t)BB * MM * DD * 2;   // 4MB
    u16* Vbf  = (u16*)p;   p += (size_t)BB * MM * DD * 2;   // 4MB
    int* knn  = (int*)p;   p += (size_t)BB * NN * KNN * 4;  // 256KB
    float4* tgt4 = (float4*)p; p += (size_t)BB * MM * 16;   // 128KB

    dim3 blk(256);
    prep<<<112, blk, 0, stream>>>(Wq, Wk, Wv, Wo1, Wo2, WTq, WTk, WTv, WTo1, WTo2,
                                  tgt, tgt4);
    mega_kernel<<<2304, blk, 0, stream>>>(src, tgt, tgt4, knn, tgt_fea, src_fea, WTq, WTk,
                                          bq, bk, bv, Qb, Kbf, Vbf, avg);
    tail_kernel<<<512, dim3(512), 0, stream>>>(Qb, Kbf, Vbf, knn, src_fea,
                                               WTo1, bo1, lng, lnb, WTo2, bo2,
                                               updated, avg);
}